// Round 13
// baseline (124.515 us; speedup 1.0000x reference)
//
#include <hip/hip_runtime.h>
#include <hip/hip_cooperative_groups.h>
#include <math.h>

namespace cg = cooperative_groups;

namespace {
constexpr int   KMAX   = 12;
constexpr int   NLINE  = 313;                   // half-space (h,k) lines
constexpr int   NL25   = 25;
constexpr int   NKV    = NLINE * NL25;          // 7825 (13 masked in phase 2)
constexpr int   NG     = NLINE * 5;             // 1565 l-groups of 5
constexpr int   GPAD   = 7 * 256;               // 1792 padded groups
constexpr int   KROW   = GPAD * 5;              // 8960 float2 per slice row
constexpr int   NSLICE = 128;                   // particle slices
constexpr int   PART   = 32;                    // particles per slice
constexpr int   S2_BLOCKS = (NKV + 63) / 64;    // 123 (64 kvecs per block)
constexpr float ALPHA_  = 0.34f;
constexpr float TWO_PI_ = 6.283185307179586f;
}

__device__ __forceinline__ void cofactors(const float* __restrict__ box,
                                          float C[3][3], float* det) {
  const float b00 = box[0], b01 = box[1], b02 = box[2];
  const float b10 = box[3], b11 = box[4], b12 = box[5];
  const float b20 = box[6], b21 = box[7], b22 = box[8];
  C[0][0] =  (b11 * b22 - b12 * b21);
  C[0][1] = -(b10 * b22 - b12 * b20);
  C[0][2] =  (b10 * b21 - b11 * b20);
  C[1][0] = -(b01 * b22 - b02 * b21);
  C[1][1] =  (b00 * b22 - b02 * b20);
  C[1][2] = -(b00 * b21 - b01 * b20);
  C[2][0] =  (b01 * b12 - b02 * b11);
  C[2][1] = -(b00 * b12 - b02 * b10);
  C[2][2] =  (b00 * b11 - b01 * b10);
  *det = b00 * C[0][0] + b01 * C[0][1] + b02 * C[0][2];
}

// Half-space lines: L<300: h=1..12 x k=-12..12; L=300..311: h=0,k=1..12; L=312: h=k=0.
__device__ __forceinline__ void line_hk(int L, int* h, int* k) {
  if (L < 300)      { *h = L / 25 + 1; *k = L % 25 - 12; }
  else if (L < 312) { *h = 0;          *k = L - 299;     }
  else              { *h = 0;          *k = 0;           }
}

// ONE cooperative kernel: phase 1 = transposed partial structure factors
// (lane = l-group of 5, loop = particles via LDS broadcast); grid.sync();
// phase 2 = slice-sum + |S|^2 * fac reduction on the first 123 blocks.
__global__ __launch_bounds__(256, 4) void ewald_fused(
    const float* __restrict__ coords, const float* __restrict__ box,
    const float* __restrict__ q, int N, float2* __restrict__ partial,
    float* __restrict__ out)
{
  __shared__ float4 sf4[PART];   // (a, b, cr, sr)
  __shared__ float2 sf2[PART];   // (c, q)
  __shared__ float  red[256];

  const int slice = blockIdx.y;
  if (blockIdx.x == 0 && slice == 0 && threadIdx.x == 0) out[0] = 0.0f;

  // ---- phase 1: stage this slice's 32 particles (threads 0..31)
  if (threadIdx.x < PART) {
    float C[3][3], det;
    cofactors(box, C, &det);
    const float invdet = 1.0f / det;
    const int i = slice * PART + threadIdx.x;
    float4 v4 = make_float4(0.f, 0.f, 1.f, 0.f);
    float2 v2 = make_float2(0.f, 0.f);
    if (i < N) {
      const float x = coords[3 * i + 0];
      const float y = coords[3 * i + 1];
      const float z = coords[3 * i + 2];
      v4.x = (x * C[0][0] + y * C[0][1] + z * C[0][2]) * invdet;   // a
      v4.y = (x * C[1][0] + y * C[1][1] + z * C[1][2]) * invdet;   // b
      float c = (x * C[2][0] + y * C[2][1] + z * C[2][2]) * invdet;
      c = c - floorf(c);                                           // c in [0,1)
      float cr, sr;
      asm("v_sin_f32 %0, %1" : "=v"(sr) : "v"(c));                 // e^{2*pi*i*c}
      asm("v_cos_f32 %0, %1" : "=v"(cr) : "v"(c));
      v4.z = cr; v4.w = sr;
      v2.x = c;  v2.y = q[i];
    }
    sf4[threadIdx.x] = v4;
    sf2[threadIdx.x] = v2;
  }
  __syncthreads();

  // ---- each thread owns group gg: line L = gg/5, l0 = -12 + 5*(gg%5)
  const int gg  = blockIdx.x * 256 + threadIdx.x;
  const int ggc = (gg < NG) ? gg : (NG - 1);
  int h, k; line_hk(ggc / 5, &h, &k);
  const float hf  = (float)h;
  const float kf  = (float)k;
  const float l0f = (float)(-KMAX + 5 * (ggc % 5));

  float Sre[5] = {0.f, 0.f, 0.f, 0.f, 0.f};
  float Sim[5] = {0.f, 0.f, 0.f, 0.f, 0.f};

#pragma unroll 2
  for (int j = 0; j < PART; ++j) {
    const float4 p = sf4[j];   // block-uniform address -> LDS broadcast
    const float2 w = sf2[j];
    float t0 = fmaf(hf, p.x, fmaf(kf, p.y, l0f * w.x));  // phase(l0), revolutions
    float tf;
    asm("v_fract_f32 %0, %1" : "=v"(tf) : "v"(t0));
    float s0, c0;
    asm("v_sin_f32 %0, %1" : "=v"(s0) : "v"(tf));
    asm("v_cos_f32 %0, %1" : "=v"(c0) : "v"(tf));
    float Pre = w.y * c0, Pim = w.y * s0;                // q folded into phasor
    Sre[0] += Pre; Sim[0] += Pim;
    const float cr = p.z, sr = p.w;
#pragma unroll
    for (int u = 1; u < 5; ++u) {
      const float nre = fmaf(Pre, cr, -(Pim * sr));
      const float nim = fmaf(Pre, sr,  (Pim * cr));
      Pre = nre; Pim = nim;
      Sre[u] += Pre; Sim[u] += Pim;
    }
  }

  // ---- store: [slice][kvidx] (kvidx = gg*5+u = L*25+ls); 40B/lane contiguous
  if (gg < NG) {
    float2* dst = partial + (size_t)slice * KROW + gg * 5;
#pragma unroll
    for (int u = 0; u < 5; ++u) dst[u] = make_float2(Sre[u], Sim[u]);
  }

  // ==== grid-wide barrier: all partials visible device-wide after this ====
  cg::this_grid().sync();

  // ---- phase 2 on the first S2_BLOCKS blocks (flattened id)
  const int sid = blockIdx.y * 7 + blockIdx.x;
  if (sid >= S2_BLOCKS) return;

  const int lane = threadIdx.x & 63;
  const int sq   = lane >> 4;         // s-quarter: 32 slices each
  const int kvl  = lane & 15;
  const int kv   = sid * 64 + (threadIdx.x >> 6) * 16 + kvl;

  float Re = 0.f, Im = 0.f;
  bool valid = false;
  int h2 = 0, k2i = 0, l2 = 0;
  if (kv < NKV) {
    const int L  = kv / NL25;
    const int ls = kv % NL25;
    l2 = ls - KMAX;
    line_hk(L, &h2, &k2i);
    valid = !(h2 == 0 && k2i == 0 && l2 <= 0);   // mask non-half-space entries
    for (int s = sq * 32; s < sq * 32 + 32; ++s) {
      const float2 p = partial[(size_t)s * KROW + kv];
      Re += p.x; Im += p.y;
    }
  }
  Re += __shfl_xor(Re, 16); Re += __shfl_xor(Re, 32);
  Im += __shfl_xor(Im, 16); Im += __shfl_xor(Im, 32);

  float e = 0.f;
  if (kv < NKV && valid && sq == 0) {
    float C[3][3], det;
    cofactors(box, C, &det);
    const float invdet = 1.0f / det;
    const float hf2 = (float)h2, kf2 = (float)k2i, lf2 = (float)l2;
    const float kx = (hf2 * C[0][0] + kf2 * C[1][0] + lf2 * C[2][0]) * invdet;
    const float ky = (hf2 * C[0][1] + kf2 * C[1][1] + lf2 * C[2][1]) * invdet;
    const float kz = (hf2 * C[0][2] + kf2 * C[1][2] + lf2 * C[2][2]) * invdet;
    const float kk = TWO_PI_ * TWO_PI_ * (kx * kx + ky * ky + kz * kz);
    const float fac = __expf(-kk / (4.0f * ALPHA_ * ALPHA_)) / kk;
    e = fac * fmaf(Re, Re, Im * Im);
  }
  red[threadIdx.x] = e;
  __syncthreads();
  for (int s = 128; s > 0; s >>= 1) {
    if (threadIdx.x < s) red[threadIdx.x] += red[threadIdx.x + s];
    __syncthreads();
  }
  if (threadIdx.x == 0) {
    float C[3][3], det;
    cofactors(box, C, &det);
    // E = (2*pi/V)*full_sum = (4*pi/V)*half_sum
    const float scale = (4.0f * 3.14159265358979323846f) / fabsf(det);
    atomicAdd(out, scale * red[0]);
  }
}

extern "C" void kernel_launch(void* const* d_in, const int* in_sizes, int n_in,
                              void* d_out, int out_size, void* d_ws, size_t ws_size,
                              hipStream_t stream) {
  const float* coords = (const float*)d_in[0];
  const float* box    = (const float*)d_in[1];
  const float* q      = (const float*)d_in[2];
  float* out = (float*)d_out;
  int N = in_sizes[2];

  // ws: partial = NSLICE * KROW float2 = 9,175,040 B
  float2* partial = (float2*)d_ws;

  void* args[] = { (void*)&coords, (void*)&box, (void*)&q, (void*)&N,
                   (void*)&partial, (void*)&out };
  hipLaunchCooperativeKernel((const void*)ewald_fused,
                             dim3(7, NSLICE), dim3(256), args, 0, stream);
}

// Round 14
// 21.123 us; speedup vs baseline: 5.8947x; 5.8947x over previous
//
#include <hip/hip_runtime.h>
#include <math.h>

namespace {
constexpr int   KMAX   = 12;
constexpr int   NLINE  = 313;                    // half-space (h,k) lines
constexpr int   NGROUP = NLINE * 5;              // 1565 l-groups of 5
constexpr int   NKV    = NGROUP * 5;             // 7825 computed k-vecs (13 masked)
constexpr int   NSLICE = 8;                      // particle slices
constexpr int   SLICE_CAP = 512;                 // staged particles per chunk
constexpr int   S2_BLOCKS = (NKV + 255) / 256;   // 31
constexpr float ALPHA_  = 0.34f;
constexpr float TWO_PI_ = 6.283185307179586f;
}

__device__ __forceinline__ void cofactors(const float* __restrict__ box,
                                          float C[3][3], float* det) {
  const float b00 = box[0], b01 = box[1], b02 = box[2];
  const float b10 = box[3], b11 = box[4], b12 = box[5];
  const float b20 = box[6], b21 = box[7], b22 = box[8];
  C[0][0] =  (b11 * b22 - b12 * b21);
  C[0][1] = -(b10 * b22 - b12 * b20);
  C[0][2] =  (b10 * b21 - b11 * b20);
  C[1][0] = -(b01 * b22 - b02 * b21);
  C[1][1] =  (b00 * b22 - b02 * b20);
  C[1][2] = -(b00 * b21 - b01 * b20);
  C[2][0] =  (b01 * b12 - b02 * b11);
  C[2][1] = -(b00 * b12 - b02 * b10);
  C[2][2] =  (b00 * b11 - b01 * b10);
  *det = b00 * C[0][0] + b01 * C[0][1] + b02 * C[0][2];
}

// Half-space lines: L<300: h=1..12 x k=-12..12; L=300..311: h=0,k=1..12; L=312: h=k=0.
__device__ __forceinline__ void line_hk(int L, int* h, int* k) {
  if (L < 300)      { *h = L / 25 + 1; *k = L % 25 - 12; }
  else if (L < 312) { *h = 0;          *k = L - 299;     }
  else              { *h = 0;          *k = 0;           }
}

// One wave = one l-group (5 l of one (h,k) line) x one particle slice.
// vs R6: rotator sincos hoisted to staging (2 trans/iter saved), unroll-4
// inner loop (4 independent phasor chains/lane), partial stored [kv][slice].
__global__ __launch_bounds__(256) void ewald_groups(
    const float* __restrict__ coords, const float* __restrict__ box,
    const float* __restrict__ q, int N, float2* __restrict__ partial,
    float* __restrict__ out)
{
  __shared__ float4 sf4[SLICE_CAP];   // (a, b, cr, sr)
  __shared__ float2 sf2[SLICE_CAP];   // (c, q)

  if (blockIdx.x == 0 && blockIdx.y == 0 && threadIdx.x == 0) out[0] = 0.0f;

  float C[3][3], det;
  cofactors(box, C, &det);
  const float invdet = 1.0f / det;

  const int slice = blockIdx.y;
  const int sp    = (N + NSLICE - 1) / NSLICE;
  const int s_beg = slice * sp;
  const int s_end = min(s_beg + sp, N);

  const int lane = threadIdx.x & 63;
  const int g    = blockIdx.x * 4 + (threadIdx.x >> 6);
  const int gc   = (g < NGROUP) ? g : (NGROUP - 1);   // clamp for decode; store guarded

  int h, k; line_hk(gc / 5, &h, &k);
  const float hf  = (float)h;
  const float kf  = (float)k;
  const float l0f = (float)(-KMAX + 5 * (gc % 5));

  float Sre[5] = {0.f, 0.f, 0.f, 0.f, 0.f};
  float Sim[5] = {0.f, 0.f, 0.f, 0.f, 0.f};

  for (int cb = s_beg; cb < s_end; cb += SLICE_CAP) {
    const int cnt = min(SLICE_CAP, s_end - cb);
    __syncthreads();
    // Stage frac coords + rotator phasor + charge (pad with q=0, rotator=1).
    for (int t = threadIdx.x; t < SLICE_CAP; t += 256) {
      float4 v4 = make_float4(0.f, 0.f, 1.f, 0.f);
      float2 v2 = make_float2(0.f, 0.f);
      if (t < cnt) {
        const int gi = cb + t;
        const float x = coords[3 * gi + 0];
        const float y = coords[3 * gi + 1];
        const float z = coords[3 * gi + 2];
        v4.x = (x * C[0][0] + y * C[0][1] + z * C[0][2]) * invdet;  // a
        v4.y = (x * C[1][0] + y * C[1][1] + z * C[1][2]) * invdet;  // b
        float c = (x * C[2][0] + y * C[2][1] + z * C[2][2]) * invdet;
        c = c - floorf(c);                                          // c in [0,1)
        float cr, sr;
        asm("v_sin_f32 %0, %1" : "=v"(sr) : "v"(c));                // e^{2*pi*i*c}
        asm("v_cos_f32 %0, %1" : "=v"(cr) : "v"(c));
        v4.z = cr; v4.w = sr;
        v2.x = c;  v2.y = q[gi];
      }
      sf4[t] = v4; sf2[t] = v2;
    }
    __syncthreads();

#pragma unroll 4
    for (int i = lane; i < SLICE_CAP; i += 64) {
      const float4 p = sf4[i];
      const float2 w = sf2[i];
      float t0 = fmaf(hf, p.x, fmaf(kf, p.y, l0f * w.x));  // phase(l0), revolutions
      float tf;
      asm("v_fract_f32 %0, %1" : "=v"(tf) : "v"(t0));
      float s0, c0;
      asm("v_sin_f32 %0, %1" : "=v"(s0) : "v"(tf));
      asm("v_cos_f32 %0, %1" : "=v"(c0) : "v"(tf));
      float Pre = w.y * c0, Pim = w.y * s0;                // q folded into phasor
      Sre[0] += Pre; Sim[0] += Pim;
      const float cr = p.z, sr = p.w;
#pragma unroll
      for (int u = 1; u < 5; ++u) {
        const float nre = fmaf(Pre, cr, -(Pim * sr));
        const float nim = fmaf(Pre, sr,  (Pim * cr));
        Pre = nre; Pim = nim;
        Sre[u] += Pre; Sim[u] += Pim;
      }
    }
  }

#pragma unroll
  for (int off = 32; off > 0; off >>= 1) {
#pragma unroll
    for (int u = 0; u < 5; ++u) {
      Sre[u] += __shfl_down(Sre[u], off);
      Sim[u] += __shfl_down(Sim[u], off);
    }
  }
  if (g < NGROUP && lane == 0) {
    // layout: partial[(g*5+u) * NSLICE + slice] -> stage2 reads dense runs
#pragma unroll
    for (int u = 0; u < 5; ++u)
      partial[(size_t)(g * 5 + u) * NSLICE + slice] = make_float2(Sre[u], Sim[u]);
  }
}

// Sum the 8 slice-partials per kvec (dense 64B run), weight by fac, reduce,
// one atomicAdd per block.
__global__ __launch_bounds__(256) void stage2(
    const float2* __restrict__ partial, const float* __restrict__ box,
    float* __restrict__ out)
{
  __shared__ float red[256];
  const int idx = blockIdx.x * 256 + threadIdx.x;
  float e = 0.f;
  if (idx < NKV) {
    const int g = idx / 5, u = idx % 5;
    const int L = g / 5, sub = g % 5;
    int h, k; line_hk(L, &h, &k);
    const int l = -KMAX + 5 * sub + u;
    if (!(h == 0 && k == 0 && l <= 0)) {   // mask the 13 non-half-space entries
      float re = 0.f, im = 0.f;
      const float2* p = partial + (size_t)idx * NSLICE;
#pragma unroll
      for (int s = 0; s < NSLICE; ++s) { re += p[s].x; im += p[s].y; }
      float C[3][3], det;
      cofactors(box, C, &det);
      const float invdet = 1.0f / det;
      const float hf = (float)h, kf = (float)k, lf = (float)l;
      const float kx = (hf * C[0][0] + kf * C[1][0] + lf * C[2][0]) * invdet;
      const float ky = (hf * C[0][1] + kf * C[1][1] + lf * C[2][1]) * invdet;
      const float kz = (hf * C[0][2] + kf * C[1][2] + lf * C[2][2]) * invdet;
      const float k2 = TWO_PI_ * TWO_PI_ * (kx * kx + ky * ky + kz * kz);
      const float fac = __expf(-k2 / (4.0f * ALPHA_ * ALPHA_)) / k2;
      e = fac * fmaf(re, re, im * im);
    }
  }
  red[threadIdx.x] = e;
  __syncthreads();
  for (int s = 128; s > 0; s >>= 1) {
    if (threadIdx.x < s) red[threadIdx.x] += red[threadIdx.x + s];
    __syncthreads();
  }
  if (threadIdx.x == 0) {
    float C[3][3], det;
    cofactors(box, C, &det);
    // E = (2*pi/V)*full_sum = (4*pi/V)*half_sum
    const float scale = (4.0f * 3.14159265358979323846f) / fabsf(det);
    atomicAdd(out, scale * red[0]);
  }
}

extern "C" void kernel_launch(void* const* d_in, const int* in_sizes, int n_in,
                              void* d_out, int out_size, void* d_ws, size_t ws_size,
                              hipStream_t stream) {
  const float* coords = (const float*)d_in[0];
  const float* box    = (const float*)d_in[1];
  const float* q      = (const float*)d_in[2];
  float* out = (float*)d_out;
  const int N = in_sizes[2];

  // ws: partial = NKV * NSLICE float2 = 500,800 B
  float2* partial = (float2*)d_ws;

  const dim3 grid((NGROUP + 3) / 4, NSLICE);   // 392 x 8 = 3136 blocks
  hipLaunchKernelGGL(ewald_groups, grid, dim3(256), 0, stream,
                     coords, box, q, N, partial, out);
  hipLaunchKernelGGL(stage2, dim3(S2_BLOCKS), dim3(256), 0, stream,
                     partial, box, out);
}